// Round 6
// baseline (1475.219 us; speedup 1.0000x reference)
//
#include <hip/hip_runtime.h>
#include <hip/hip_fp16.h>

#define TS 40
#define NB 2048
#define NU 1024
#define NI 1024
#define ND 2048
#define UD (1024 * 2048)  // elems in one W_t (4 MB as f16)

typedef _Float16 half8 __attribute__((ext_vector_type(8)));
typedef _Float16 half4v __attribute__((ext_vector_type(4)));
typedef float floatx4 __attribute__((ext_vector_type(4)));

__device__ __forceinline__ float tanh_fast(float v) {
  float e = __expf(2.0f * v);
  return 1.0f - 2.0f / (e + 1.0f);  // inf-safe
}

// async global->LDS, 16B per lane
__device__ __forceinline__ void gload16(const void* g, void* l) {
  __builtin_amdgcn_global_load_lds(
      (const __attribute__((address_space(1))) void*)g,
      (__attribute__((address_space(3))) void*)l, 16, 0, 0);
}

// ===== fragment-major tile layout ===========================================
// tile = 64 rows x 64 cols f16 = 8192 B, stored as 512 x 16B chunks.
// chunk(r, c8) = ((r>>4)*2 + (c8>>2))*64 + (c8&3)*16 + (r&15)
// A wave's MFMA fragment read (rows Rb*16+l15, k-slice kk*32+lk*8) is then
// chunk base + lane  ->  ds_read_b128 at wave-uniform base + lane*16 (linear,
// bank-conflict-free). gload_lds DMA writes tiles linearly.
__device__ __forceinline__ int tile_off(int r, int c8) {
  return (((((r >> 4) * 2 + (c8 >> 2)) << 6) + ((c8 & 3) << 4) + (r & 15)) << 4);
}

// W_tiled:  [t][ut 0..15][kt 0..31][8192B]  (kt<16: h-part, kt>=16: x-part)
// X_tiled:  [t][bt 0..31][kt 0..15][8192B]
// h_tiled:  [slot][bt 0..31][kt 0..15][8192B]   (k dim of h = u)
// pre:      [slot][bid][tid][16 f16]  fragment order idx = ((mf*2+nf)<<2)+j

// ---------------- wprep: Qw (fp32) -> W tiled f16 ---------------------------
// block (kt, ut) covers k=kt*64.., u=ut*64.., all 40 t. 256 thr.
__global__ __launch_bounds__(256) void wprep(
    const float* __restrict__ Qw, const float* __restrict__ Bt,
    _Float16* __restrict__ W)
{
  __shared__ _Float16 ldsQ[64 * 512];  // [dk][du*8+q], 64 KB
  __shared__ float ldsB[TS * 8];
  const int tid = threadIdx.x;
  const int kt = blockIdx.x;   // 0..31
  const int ut = blockIdx.y;   // 0..15
  for (int i = tid; i < TS * 8; i += 256) ldsB[i] = Bt[i];
  const float* qb = Qw + (size_t)(kt * 64) * 8192 + ut * 512;
#pragma unroll
  for (int i = 0; i < 32; ++i) {
    int s = i * 256 + tid;          // 0..8191
    int dk = s >> 7, c4 = s & 127;  // k-row, float4-col
    float4 v = *(const float4*)(qb + (size_t)dk * 8192 + c4 * 4);
    _Float16* d = &ldsQ[dk * 512 + c4 * 4];
    d[0] = (_Float16)v.x; d[1] = (_Float16)v.y;
    d[2] = (_Float16)v.z; d[3] = (_Float16)v.w;
  }
  __syncthreads();
  const int w = tid >> 6, lane = tid & 63;
  const int dur = lane & 7, ko = lane >> 3;  // row-within-octet, c8
#pragma unroll 1
  for (int sp = 0; sp < 2; ++sp) {
    const int stripe = w * 2 + sp;
    const int du = stripe * 8 + dur;         // u within tile 0..63
    float Q[8][8];                           // [j = k-col][q]
#pragma unroll
    for (int j = 0; j < 8; ++j)
#pragma unroll
      for (int q = 0; q < 8; ++q)
        Q[j][q] = (float)ldsQ[(ko * 8 + j) * 512 + du * 8 + q];
    const int obase = tile_off(du, ko);
#pragma unroll 1
    for (int t = 0; t < TS; ++t) {
      float b[8];
#pragma unroll
      for (int q = 0; q < 8; ++q) b[q] = ldsB[t * 8 + q];
      half8 v;
#pragma unroll
      for (int j = 0; j < 8; ++j) {
        float s = 0.f;
#pragma unroll
        for (int q = 0; q < 8; ++q) s += Q[j][q] * b[q];
        v[j] = (_Float16)s;
      }
      size_t tile = ((size_t)t * 16 + ut) * 32 + kt;
      *(half8*)((char*)W + tile * 8192 + obase) = v;
    }
  }
}

// ---------------- xprep: x fp32 -> X tiled f16 ------------------------------
// grid (32, 40): bt, t. 16 tiles (kt) per block.
__global__ __launch_bounds__(256) void xprep(
    const float* __restrict__ x, _Float16* __restrict__ X)
{
  const int tid = threadIdx.x;
  const int bt = blockIdx.x, t = blockIdx.y;
  char* tb0 = (char*)X + ((size_t)(t * 32 + bt) * 16) * 8192;
#pragma unroll 1
  for (int kt = 0; kt < 16; ++kt) {
#pragma unroll
    for (int it = 0; it < 2; ++it) {
      int rc = it * 256 + tid;        // 0..511
      int r = rc >> 3, c8 = rc & 7;
      const float* src = x + (size_t)(bt * 64 + r) * (TS * NI) + t * NI + kt * 64 + c8 * 8;
      float4 v0 = *(const float4*)src;
      float4 v1 = *(const float4*)(src + 4);
      half8 h;
      h[0] = (_Float16)v0.x; h[1] = (_Float16)v0.y;
      h[2] = (_Float16)v0.z; h[3] = (_Float16)v0.w;
      h[4] = (_Float16)v1.x; h[5] = (_Float16)v1.y;
      h[6] = (_Float16)v1.z; h[7] = (_Float16)v1.w;
      *(half8*)(tb0 + (size_t)kt * 8192 + tile_off(r, c8)) = h;
    }
  }
}

// ---------------- hinit: h0 fp32 -> h tiled f16 (slot 0) --------------------
__global__ __launch_bounds__(256) void hinit(const float* __restrict__ h0,
                                             _Float16* __restrict__ hb) {
  int g = blockIdx.x * 256 + threadIdx.x;   // 262144 chunks
  int tile_id = g >> 9, rc = g & 511;
  int bt = tile_id >> 4, kt = tile_id & 15;
  int r = rc >> 3, c8 = rc & 7;
  const float* src = h0 + (size_t)(bt * 64 + r) * NU + kt * 64 + c8 * 8;
  float4 v0 = *(const float4*)src;
  float4 v1 = *(const float4*)(src + 4);
  half8 h;
  h[0] = (_Float16)v0.x; h[1] = (_Float16)v0.y;
  h[2] = (_Float16)v0.z; h[3] = (_Float16)v0.w;
  h[4] = (_Float16)v1.x; h[5] = (_Float16)v1.y;
  h[6] = (_Float16)v1.z; h[7] = (_Float16)v1.w;
  *(half8*)((char*)hb + (size_t)tile_id * 8192 + tile_off(r, c8)) = h;
}

// ---------------- fused step ------------------------------------------------
// DOH: h_t = tanh(h_{t-1} @ Wh_t + pre_t)     (16 phases, serial chain)
// DOX: pre_{t+1} = x_{t+1} @ Wx_{t+1} + bias  (16 phases, independent work)
// Interleaved phases share one DEPTH-4 gload_lds pipeline, vmcnt(12).
// 512 blocks (2/CU), 4 waves, 64x64 output tile each part.
template <bool DOH, bool DOX>
__global__ __launch_bounds__(256) void fused_step(
    const _Float16* __restrict__ Wh,    // W + t*UD
    const _Float16* __restrict__ Wx,    // W + (t+1)*UD
    const _Float16* __restrict__ Xt,    // X + (t+1)*512 tiles
    const _Float16* __restrict__ preR,  // frag slot t&1
    _Float16* __restrict__ preW,        // frag slot (t+1)&1
    const _Float16* __restrict__ hprev,
    _Float16* __restrict__ hnext,
    float* __restrict__ outt,           // out + t*NU, row stride TS*NU
    const float* __restrict__ bias)
{
  __shared__ uint4 lds4[4096];  // 64 KB: 4 bufs x (A 8KB + B 8KB)
  const int tid = threadIdx.x, bid = blockIdx.x;
  const int bt = bid & 31, ut = bid >> 5;
  const int lane = tid & 63, w = tid >> 6;
  const int wm = w >> 1, wn = w & 1;
  const int l15 = lane & 15, lk = lane >> 4;
  const int b0 = bt * 64, u0 = ut * 64;

  constexpr int NPH = (DOH ? 16 : 0) + (DOX ? 16 : 0);

  // prefetch epilogue operands (oldest vmcnt entries; safe: counted waits
  // always drain through phase p because phases p+1..p+3 are the newest 12)
  uint4 prv[2] = {};
  float bv0 = 0.f, bv1 = 0.f;
  if constexpr (DOH) {
    const uint4* pr4 = (const uint4*)(preR + ((size_t)bid * 256 + tid) * 16);
    prv[0] = pr4[0]; prv[1] = pr4[1];
  }
  if constexpr (DOX) {
    bv0 = bias[u0 + wn * 32 + l15];
    bv1 = bias[u0 + wn * 32 + 16 + l15];
  }

  const char* Hb  = (const char*)hprev + (size_t)bt * 16 * 8192;
  const char* Xb  = (const char*)Xt    + (size_t)bt * 16 * 8192;
  const char* WhB = (const char*)Wh    + (size_t)ut * 32 * 8192;
  const char* WxB = (const char*)Wx    + (size_t)ut * 32 * 8192 + (size_t)16 * 8192;

  auto issue_phase = [&](int p) {
    int kt; bool is_x;
    if constexpr (DOH && DOX) { kt = p >> 1; is_x = (p & 1) != 0; }
    else { kt = p; is_x = DOX; }
    const char* ga = (is_x ? Xb : Hb) + (size_t)kt * 8192 + w * 2048 + lane * 16;
    const char* gb = (is_x ? WxB : WhB) + (size_t)kt * 8192 + w * 2048 + lane * 16;
    char* la = (char*)lds4 + (p & 3) * 16384 + w * 2048;  // wave-uniform dest
    char* lb = la + 8192;
    gload16(ga, la); gload16(ga + 1024, la + 1024);
    gload16(gb, lb); gload16(gb + 1024, lb + 1024);
  };

  floatx4 acch[2][2] = {};
  floatx4 accx[2][2] = {};

  auto do_mfma = [&](int p, floatx4 (&acc)[2][2]) {
    const char* pA = (const char*)lds4 + (p & 3) * 16384;
    const char* pB = pA + 8192;
    __builtin_amdgcn_s_setprio(1);
#pragma unroll
    for (int kk = 0; kk < 2; ++kk) {
      half8 af[2], bf[2];
#pragma unroll
      for (int mf = 0; mf < 2; ++mf)
        af[mf] = *(const half8*)(pA + ((((wm * 2 + mf) * 2 + kk) << 10) + lane * 16));
#pragma unroll
      for (int nf = 0; nf < 2; ++nf)
        bf[nf] = *(const half8*)(pB + ((((wn * 2 + nf) * 2 + kk) << 10) + lane * 16));
#pragma unroll
      for (int mf = 0; mf < 2; ++mf)
#pragma unroll
        for (int nf = 0; nf < 2; ++nf)
          acc[mf][nf] = __builtin_amdgcn_mfma_f32_16x16x32_f16(
              af[mf], bf[nf], acc[mf][nf], 0, 0, 0);
    }
    __builtin_amdgcn_s_setprio(0);
  };

  issue_phase(0); issue_phase(1); issue_phase(2);
#pragma unroll 2
  for (int p = 0; p < NPH; ++p) {
    if (p + 3 < NPH) issue_phase(p + 3);
    if (p < NPH - 3)       asm volatile("s_waitcnt vmcnt(12)" ::: "memory");
    else if (p == NPH - 3) asm volatile("s_waitcnt vmcnt(8)" ::: "memory");
    else if (p == NPH - 2) asm volatile("s_waitcnt vmcnt(4)" ::: "memory");
    else                   asm volatile("s_waitcnt vmcnt(0)" ::: "memory");
    __syncthreads();
    if constexpr (DOH && DOX) {
      if (p & 1) do_mfma(p, accx); else do_mfma(p, acch);
    } else if constexpr (DOX) {
      do_mfma(p, accx);
    } else {
      do_mfma(p, acch);
    }
    __syncthreads();
  }

  if constexpr (DOH) {
    const _Float16* prh = (const _Float16*)prv;
#pragma unroll
    for (int mf = 0; mf < 2; ++mf)
#pragma unroll
      for (int nf = 0; nf < 2; ++nf) {
        int u = u0 + wn * 32 + nf * 16 + l15;
        int brow = b0 + wm * 32 + mf * 16 + (lk << 2);
#pragma unroll
        for (int j = 0; j < 4; ++j) {
          int b = brow + j;
          float p = (float)prh[((mf * 2 + nf) << 2) + j];
          float v = tanh_fast(acch[mf][nf][j] + p);
          outt[(size_t)b * (TS * NU) + u] = v;
          *(_Float16*)((char*)hnext + (((size_t)(bt * 16 + ut)) << 13) +
                       tile_off(b & 63, (u & 63) >> 3) + (u & 7) * 2) = (_Float16)v;
        }
      }
  }
  if constexpr (DOX) {
    _Float16 pw[16];
#pragma unroll
    for (int mf = 0; mf < 2; ++mf)
#pragma unroll
      for (int nf = 0; nf < 2; ++nf) {
        float bv = nf ? bv1 : bv0;
#pragma unroll
        for (int j = 0; j < 4; ++j)
          pw[((mf * 2 + nf) << 2) + j] = (_Float16)(accx[mf][nf][j] + bv);
      }
    uint4* dst = (uint4*)(preW + ((size_t)bid * 256 + tid) * 16);
    dst[0] = ((const uint4*)pw)[0];
    dst[1] = ((const uint4*)pw)[1];
  }
}

// ================= round-1 fallback path (small ws) =========================
__global__ __launch_bounds__(256) void wprep_lin(
    const float* __restrict__ Qw, const float* __restrict__ Bt,
    _Float16* __restrict__ W, int t0, int nt)
{
  __shared__ float ldsQ[32 * 257];
  __shared__ float ldsB[TS * 8];
  const int tid = threadIdx.x;
  const int k0 = blockIdx.x * 32;
  const int u0 = blockIdx.y * 32;
  for (int i = tid; i < TS * 8; i += 256) ldsB[i] = Bt[i];
  const float* qbase = Qw + (size_t)k0 * 8192 + (size_t)u0 * 8;
#pragma unroll
  for (int i = 0; i < 8; ++i) {
    int s = i * 256 + tid;
    int r = s >> 6, c4 = s & 63;
    float4 v = *(const float4*)(qbase + (size_t)r * 8192 + c4 * 4);
    float* d = &ldsQ[r * 257 + c4 * 4];
    d[0] = v.x; d[1] = v.y; d[2] = v.z; d[3] = v.w;
  }
  __syncthreads();
  const int kl = tid & 31;
  const int ug = tid >> 5;
#pragma unroll
  for (int p = 0; p < 4; ++p) {
    int uu = p * 8 + ug;
    float q[8];
#pragma unroll
    for (int j = 0; j < 8; ++j) q[j] = ldsQ[kl * 257 + uu * 8 + j];
    size_t obase = (size_t)(u0 + uu) * 2048 + k0 + kl;
    for (int tt = 0; tt < nt; ++tt) {
      const float* bt = &ldsB[(t0 + tt) * 8];
      float v = 0.f;
#pragma unroll
      for (int j = 0; j < 8; ++j) v += q[j] * bt[j];
      W[(size_t)tt * UD + obase] = (_Float16)v;
    }
  }
}

__global__ __launch_bounds__(256) void step_gemm(
    const float* __restrict__ xt, const float* __restrict__ hp, long hstride,
    const _Float16* __restrict__ Wt, const float* __restrict__ bias,
    float* __restrict__ outt)
{
  __shared__ _Float16 ldsA[2][64 * 64];
  __shared__ _Float16 ldsB[2][128 * 64];
  const int tid = threadIdx.x;
  const int b0 = blockIdx.x * 64;
  const int u0 = blockIdx.y * 128;
  const int lane = tid & 63;
  const int wv = tid >> 6;
  const int wm = wv >> 1, wn = wv & 1;
  const int l15 = lane & 15, lk = lane >> 4;

  float4 areg[4];
  uint4 breg[4];

  auto stage_load = [&](int kt) {
    const int k0 = kt * 64;
    const float* src; size_t stride; int koff;
    if (k0 < NU) { src = hp; stride = (size_t)hstride; koff = k0; }
    else { src = xt; stride = (size_t)TS * NI; koff = k0 - NU; }
#pragma unroll
    for (int i = 0; i < 4; ++i) {
      int s = i * 256 + tid;
      int r = s >> 4, c4 = s & 15;
      areg[i] = *(const float4*)(src + (size_t)(b0 + r) * stride + koff + c4 * 4);
    }
    const _Float16* wsrc = Wt + (size_t)u0 * 2048 + k0;
#pragma unroll
    for (int i = 0; i < 4; ++i) {
      int s = i * 256 + tid;
      int u = s >> 3, c8 = s & 7;
      breg[i] = *(const uint4*)(wsrc + (size_t)u * 2048 + c8 * 8);
    }
  };

  auto stage_write = [&](int buf) {
    char* pA = (char*)&ldsA[buf][0];
    char* pB = (char*)&ldsB[buf][0];
#pragma unroll
    for (int i = 0; i < 4; ++i) {
      int s = i * 256 + tid;
      int r = s >> 4, c4 = s & 15;
      half4v h;
      h[0] = (_Float16)areg[i].x; h[1] = (_Float16)areg[i].y;
      h[2] = (_Float16)areg[i].z; h[3] = (_Float16)areg[i].w;
      int off = (r * 128 + c4 * 8) ^ ((r & 7) << 4);
      *(half4v*)(pA + off) = h;
    }
#pragma unroll
    for (int i = 0; i < 4; ++i) {
      int s = i * 256 + tid;
      int u = s >> 3, c8 = s & 7;
      int off = (u * 128 + c8 * 16) ^ ((u & 7) << 4);
      *(uint4*)(pB + off) = breg[i];
    }
  };

  floatx4 acc[2][4] = {};

  auto compute = [&](int buf) {
    const char* pA = (const char*)&ldsA[buf][0];
    const char* pB = (const char*)&ldsB[buf][0];
#pragma unroll
    for (int kk = 0; kk < 2; ++kk) {
      half8 af[2], bf[4];
#pragma unroll
      for (int mf = 0; mf < 2; ++mf) {
        int r = wm * 32 + mf * 16 + l15;
        int off = r * 128 + ((((kk << 2) | lk) ^ (r & 7)) << 4);
        af[mf] = *(const half8*)(pA + off);
      }
#pragma unroll
      for (int nf = 0; nf < 4; ++nf) {
        int u = wn * 64 + nf * 16 + l15;
        int off = u * 128 + ((((kk << 2) | lk) ^ (u & 7)) << 4);
        bf[nf] = *(const half8*)(pB + off);
      }
#pragma unroll
      for (int mf = 0; mf < 2; ++mf)
#pragma unroll
        for (int nf = 0; nf < 4; ++nf)
          acc[mf][nf] =
              __builtin_amdgcn_mfma_f32_16x16x32_f16(af[mf], bf[nf], acc[mf][nf], 0, 0, 0);
    }
  };

  stage_load(0);
  stage_write(0);
  __syncthreads();
#pragma unroll 1
  for (int kt = 0; kt < 32; ++kt) {
    int cur = kt & 1;
    if (kt + 1 < 32) stage_load(kt + 1);
    compute(cur);
    if (kt + 1 < 32) stage_write(cur ^ 1);
    __syncthreads();
  }

#pragma unroll
  for (int mf = 0; mf < 2; ++mf)
#pragma unroll
    for (int nf = 0; nf < 4; ++nf) {
      int u = u0 + wn * 64 + nf * 16 + l15;
      float bv = bias[u];
      int brow = b0 + wm * 32 + mf * 16 + (lk << 2);
#pragma unroll
      for (int j = 0; j < 4; ++j) {
        float prev = acc[mf][nf][j] + bv;
        outt[(size_t)(brow + j) * (TS * NU) + u] = tanh_fast(prev);
      }
    }
}

extern "C" void kernel_launch(void* const* d_in, const int* in_sizes, int n_in,
                              void* d_out, int out_size, void* d_ws, size_t ws_size,
                              hipStream_t stream) {
  const float* x    = (const float*)d_in[0];
  const float* h0   = (const float*)d_in[1];
  const float* Qw   = (const float*)d_in[2];
  const float* bias = (const float*)d_in[3];
  const float* Bt   = (const float*)d_in[4];
  float* out = (float*)d_out;

  char* ws = (char*)d_ws;
  const size_t w_bytes    = (size_t)UD * TS * sizeof(_Float16);      // 167.8 MB
  const size_t x_bytes    = w_bytes;                                 // 167.8 MB
  const size_t slot_bytes = (size_t)NB * NU * sizeof(_Float16);      // 4 MB
  const size_t need = w_bytes + x_bytes + 4 * slot_bytes;            // ~352 MB

  if (ws_size >= need) {
    _Float16* W    = (_Float16*)ws;
    _Float16* X    = (_Float16*)(ws + w_bytes);
    _Float16* preb = (_Float16*)(ws + w_bytes + x_bytes);
    _Float16* hb   = (_Float16*)(ws + w_bytes + x_bytes + 2 * slot_bytes);
    const size_t SLOT = (size_t)NB * NU;  // elems

    wprep<<<dim3(32, 16), 256, 0, stream>>>(Qw, Bt, W);
    xprep<<<dim3(32, 40), 256, 0, stream>>>(x, X);
    hinit<<<dim3(1024), 256, 0, stream>>>(h0, hb);  // slot 0

    // bootstrap: pre_0 only (t = -1)
    fused_step<false, true><<<dim3(512), 256, 0, stream>>>(
        W, W, X, preb, preb, hb, hb, out, bias);

    for (int t = 0; t < TS; ++t) {
      const _Float16* Wh = W + (size_t)t * UD;
      const _Float16* Wx = (t + 1 < TS) ? W + (size_t)(t + 1) * UD : W;
      const _Float16* Xt = (t + 1 < TS)
          ? (const _Float16*)((char*)X + (size_t)(t + 1) * 512 * 8192) : X;
      const _Float16* preR = preb + (size_t)(t & 1) * SLOT;
      _Float16* preW = preb + (size_t)((t + 1) & 1) * SLOT;
      const _Float16* hprev = hb + (size_t)(t & 1) * SLOT;
      _Float16* hnext = hb + (size_t)((t + 1) & 1) * SLOT;
      float* outt = out + (size_t)t * NU;
      if (t + 1 < TS)
        fused_step<true, true><<<dim3(512), 256, 0, stream>>>(
            Wh, Wx, Xt, preR, preW, hprev, hnext, outt, bias);
      else
        fused_step<true, false><<<dim3(512), 256, 0, stream>>>(
            Wh, Wx, Xt, preR, preW, hprev, hnext, outt, bias);
    }
  } else {
    // round-1 fallback (linear W layout)
    _Float16* W = (_Float16*)ws;
    const bool big = ws_size >= w_bytes;
    if (big) wprep_lin<<<dim3(64, 32), 256, 0, stream>>>(Qw, Bt, W, 0, TS);
    for (int t = 0; t < TS; ++t) {
      const _Float16* Wtp;
      if (big) {
        Wtp = W + (size_t)t * UD;
      } else {
        wprep_lin<<<dim3(64, 32), 256, 0, stream>>>(Qw, Bt, W, t, 1);
        Wtp = W;
      }
      const float* hp = (t == 0) ? h0 : out + (size_t)(t - 1) * NU;
      long hstride = (t == 0) ? NU : (long)TS * NU;
      step_gemm<<<dim3(32, 8), 256, 0, stream>>>(
          x + (size_t)t * NI, hp, hstride, Wtp, bias, out + (size_t)t * NU);
    }
  }
}

// Round 7
// 949.597 us; speedup vs baseline: 1.5535x; 1.5535x over previous
//
#include <hip/hip_runtime.h>
#include <hip/hip_fp16.h>

#define TS 40
#define NB 2048
#define NU 1024
#define NI 1024
#define ND 2048
#define UD (1024 * 2048)  // elems in one W_t (4 MB as f16)

typedef _Float16 half8 __attribute__((ext_vector_type(8)));
typedef _Float16 half4v __attribute__((ext_vector_type(4)));
typedef float floatx4 __attribute__((ext_vector_type(4)));

__device__ __forceinline__ float tanh_fast(float v) {
  float e = __expf(2.0f * v);
  return 1.0f - 2.0f / (e + 1.0f);  // inf-safe
}

// async global->LDS, 16B per lane
__device__ __forceinline__ void gload16(const void* g, void* l) {
  __builtin_amdgcn_global_load_lds(
      (const __attribute__((address_space(1))) void*)g,
      (__attribute__((address_space(3))) void*)l, 16, 0, 0);
}

// ===== fragment-major tile layout (R6, numerically verified) ================
// tile = 64 rows x 64 cols f16 = 8192 B, stored as 512 x 16B chunks.
// chunk(r, c8) = ((r>>4)*2 + (c8>>2))*64 + (c8&3)*16 + (r&15)
// MFMA frag read = wave-uniform base + lane*16 (conflict-free ds_read_b128).
__device__ __forceinline__ int tile_off(int r, int c8) {
  return (((((r >> 4) * 2 + (c8 >> 2)) << 6) + ((c8 & 3) << 4) + (r & 15)) << 4);
}

// W_tiled:  [t][ut 0..15][kt 0..31][8192B]  (kt<16: h-part, kt>=16: x-part)
// h_tiled:  [slot][bt 0..31][kt 0..15][8192B]   (cols of h tile = u of prev)
// pre:      [t][b][u] linear f16

// ---------------- wprep: Qw (fp32) -> W tiled f16 (R6, verified) ------------
__global__ __launch_bounds__(256) void wprep(
    const float* __restrict__ Qw, const float* __restrict__ Bt,
    _Float16* __restrict__ W)
{
  __shared__ _Float16 ldsQ[64 * 512];
  __shared__ float ldsB[TS * 8];
  const int tid = threadIdx.x;
  const int kt = blockIdx.x;   // 0..31
  const int ut = blockIdx.y;   // 0..15
  for (int i = tid; i < TS * 8; i += 256) ldsB[i] = Bt[i];
  const float* qb = Qw + (size_t)(kt * 64) * 8192 + ut * 512;
#pragma unroll
  for (int i = 0; i < 32; ++i) {
    int s = i * 256 + tid;
    int dk = s >> 7, c4 = s & 127;
    float4 v = *(const float4*)(qb + (size_t)dk * 8192 + c4 * 4);
    _Float16* d = &ldsQ[dk * 512 + c4 * 4];
    d[0] = (_Float16)v.x; d[1] = (_Float16)v.y;
    d[2] = (_Float16)v.z; d[3] = (_Float16)v.w;
  }
  __syncthreads();
  const int w = tid >> 6, lane = tid & 63;
  const int dur = lane & 7, ko = lane >> 3;
#pragma unroll 1
  for (int sp = 0; sp < 2; ++sp) {
    const int stripe = w * 2 + sp;
    const int du = stripe * 8 + dur;
    float Q[8][8];
#pragma unroll
    for (int j = 0; j < 8; ++j)
#pragma unroll
      for (int q = 0; q < 8; ++q)
        Q[j][q] = (float)ldsQ[(ko * 8 + j) * 512 + du * 8 + q];
    const int obase = tile_off(du, ko);
#pragma unroll 1
    for (int t = 0; t < TS; ++t) {
      float b[8];
#pragma unroll
      for (int q = 0; q < 8; ++q) b[q] = ldsB[t * 8 + q];
      half8 v;
#pragma unroll
      for (int j = 0; j < 8; ++j) {
        float s = 0.f;
#pragma unroll
        for (int q = 0; q < 8; ++q) s += Q[j][q] * b[q];
        v[j] = (_Float16)s;
      }
      size_t tile = ((size_t)t * 16 + ut) * 32 + kt;
      *(half8*)((char*)W + tile * 8192 + obase) = v;
    }
  }
}

// ---------------- hinit: h0 fp32 -> h tiled f16 (slot 0) (R6, verified) -----
__global__ __launch_bounds__(256) void hinit(const float* __restrict__ h0,
                                             _Float16* __restrict__ hb) {
  int g = blockIdx.x * 256 + threadIdx.x;
  int tile_id = g >> 9, rc = g & 511;
  int bt = tile_id >> 4, kt = tile_id & 15;
  int r = rc >> 3, c8 = rc & 7;
  const float* src = h0 + (size_t)(bt * 64 + r) * NU + kt * 64 + c8 * 8;
  float4 v0 = *(const float4*)src;
  float4 v1 = *(const float4*)(src + 4);
  half8 h;
  h[0] = (_Float16)v0.x; h[1] = (_Float16)v0.y;
  h[2] = (_Float16)v0.z; h[3] = (_Float16)v0.w;
  h[4] = (_Float16)v1.x; h[5] = (_Float16)v1.y;
  h[6] = (_Float16)v1.z; h[7] = (_Float16)v1.w;
  *(half8*)((char*)hb + (size_t)tile_id * 8192 + tile_off(r, c8)) = h;
}

// ---------------- xproj2: pre[t][b][u] = x_t @ Wx_t + bias ------------------
// 128x128 tile, grid (16,8,40), 256 thr = 4 waves of 64x64. Double-buffered:
// A (x fp32 -> f16 frag-major, reg-staged), B (tiled Wx via gload_lds DMA).
__global__ __launch_bounds__(256) void xproj2(
    const float* __restrict__ x, const _Float16* __restrict__ W,
    const float* __restrict__ bias, _Float16* __restrict__ pre)
{
  __shared__ char lds[2][32768];  // per buf: A 2 tiles 16KB | B 2 tiles 16KB
  const int tid = threadIdx.x;
  const int bt2 = blockIdx.x;   // 128 b-rows
  const int ut2 = blockIdx.y;   // 128 u-cols
  const int t   = blockIdx.z;
  const int lane = tid & 63, w = tid >> 6;
  const int wm2 = w >> 1, wn2 = w & 1;
  const int l15 = lane & 15, lk = lane >> 4;

  const float* xb = x + (size_t)(bt2 * 128) * (TS * NI) + (size_t)t * NI;
  // B tile (ut2*2 + ti, kt=16+p) base:
  const char* WB = (const char*)W + (((size_t)t * 16 + ut2 * 2) * 32 + 16) * 8192;

  float bv[4];
#pragma unroll
  for (int nf = 0; nf < 4; ++nf)
    bv[nf] = bias[ut2 * 128 + wn2 * 64 + nf * 16 + l15];

  float4 areg[8];

  auto loadA = [&](int p) {
#pragma unroll
    for (int i = 0; i < 8; ++i) {
      int s = i * 256 + tid;
      int r = s >> 4, c4 = s & 15;
      areg[i] = *(const float4*)(xb + (size_t)r * (TS * NI) + p * 64 + c4 * 4);
    }
  };
  auto issueB = [&](int p, int buf) {
    const char* gb = WB + (size_t)(w >> 1) * (32 * 8192) + (size_t)p * 8192 +
                     (w & 1) * 4096 + lane * 16;
    char* lb = lds[buf] + 16384 + (w >> 1) * 8192 + (w & 1) * 4096 + lane * 16;
    gload16(gb, lb);
    gload16(gb + 1024, lb + 1024);
    gload16(gb + 2048, lb + 2048);
    gload16(gb + 3072, lb + 3072);
  };
  auto writeA = [&](int buf) {
    char* pA = lds[buf];
#pragma unroll
    for (int i = 0; i < 8; ++i) {
      int s = i * 256 + tid;
      int r = s >> 4, c4 = s & 15;
      half4v h;
      h[0] = (_Float16)areg[i].x; h[1] = (_Float16)areg[i].y;
      h[2] = (_Float16)areg[i].z; h[3] = (_Float16)areg[i].w;
      *(half4v*)(pA + (r >> 6) * 8192 + tile_off(r & 63, c4 >> 1) + (c4 & 1) * 8) = h;
    }
  };

  floatx4 acc[4][4] = {};

  auto comp = [&](int buf) {
    const char* pA = lds[buf] + wm2 * 8192;
    const char* pB = lds[buf] + 16384 + wn2 * 8192;
    __builtin_amdgcn_s_setprio(1);
#pragma unroll
    for (int kk = 0; kk < 2; ++kk) {
      half8 af[4], bf[4];
#pragma unroll
      for (int mf = 0; mf < 4; ++mf)
        af[mf] = *(const half8*)(pA + (((mf * 2 + kk)) << 10) + lane * 16);
#pragma unroll
      for (int nf = 0; nf < 4; ++nf)
        bf[nf] = *(const half8*)(pB + (((nf * 2 + kk)) << 10) + lane * 16);
#pragma unroll
      for (int mf = 0; mf < 4; ++mf)
#pragma unroll
        for (int nf = 0; nf < 4; ++nf)
          acc[mf][nf] = __builtin_amdgcn_mfma_f32_16x16x32_f16(
              af[mf], bf[nf], acc[mf][nf], 0, 0, 0);
    }
    __builtin_amdgcn_s_setprio(0);
  };

  issueB(0, 0);
  loadA(0);
  writeA(0);
  __syncthreads();
#pragma unroll 1
  for (int p = 0; p < 16; ++p) {
    int cur = p & 1;
    if (p + 1 < 16) { issueB(p + 1, cur ^ 1); loadA(p + 1); }
    comp(cur);
    if (p + 1 < 16) writeA(cur ^ 1);
    __syncthreads();
  }

#pragma unroll
  for (int mf = 0; mf < 4; ++mf)
#pragma unroll
    for (int nf = 0; nf < 4; ++nf) {
      int u = ut2 * 128 + wn2 * 64 + nf * 16 + l15;
      int brow = bt2 * 128 + wm2 * 64 + mf * 16 + (lk << 2);
#pragma unroll
      for (int j = 0; j < 4; ++j)
        pre[((size_t)t * NB + brow + j) * NU + u] =
            (_Float16)(acc[mf][nf][j] + bv[nf]);
    }
}

// ---------------- serial2: h_t = tanh(h_{t-1} @ Wh_t + pre_t) ---------------
// 64x64 tile, 16 phases BK=64. Ring-4 gload_lds DMA, counted vmcnt(8),
// ONE raw s_barrier per phase (no vmcnt(0) drain!). 512 blocks (2/CU).
__global__ __launch_bounds__(256) void serial2(
    const _Float16* __restrict__ Wh,    // W + t*UD (tiled)
    const _Float16* __restrict__ pret,  // pre + t*NB*NU (linear f16)
    const _Float16* __restrict__ hprev, // tiled
    _Float16* __restrict__ hnext,       // tiled
    float* __restrict__ outt)           // out + t*NU, row stride TS*NU
{
  __shared__ uint4 lds4[4096];          // 64 KB: 4 bufs x (A 8KB | B 8KB)
  const int tid = threadIdx.x, bid = blockIdx.x;
  const int bt = bid & 31, ut = bid >> 5;
  const int lane = tid & 63, w = tid >> 6;
  const int wm = w >> 1, wn = w & 1;
  const int l15 = lane & 15, lk = lane >> 4;
  const int b0 = bt * 64, u0 = ut * 64;

  // prefetch epilogue operand (oldest vmcnt entries, drained by first wait)
  _Float16 pr[16];
#pragma unroll
  for (int mf = 0; mf < 2; ++mf)
#pragma unroll
    for (int nf = 0; nf < 2; ++nf)
#pragma unroll
      for (int j = 0; j < 4; ++j)
        pr[((mf * 2 + nf) << 2) + j] = pret[
            (size_t)(b0 + wm * 32 + mf * 16 + (lk << 2) + j) * NU +
            (u0 + wn * 32 + nf * 16 + l15)];

  const char* Hb = (const char*)hprev + (size_t)bt * 16 * 8192;
  const char* Wb = (const char*)Wh + (size_t)ut * 32 * 8192;

  auto issue = [&](int kt) {
    char* la = (char*)lds4 + (kt & 3) * 16384 + w * 2048;
    const char* ga = Hb + (size_t)kt * 8192 + w * 2048 + lane * 16;
    const char* gb = Wb + (size_t)kt * 8192 + w * 2048 + lane * 16;
    gload16(ga, la);
    gload16(ga + 1024, la + 1024);
    gload16(gb, la + 8192);
    gload16(gb + 1024, la + 8192 + 1024);
  };

  floatx4 acc[2][2] = {};

  issue(0);
  issue(1);
#pragma unroll 1
  for (int p = 0; p < 16; ++p) {
    if (p + 2 < 16) issue(p + 2);
    if (p < 14)       asm volatile("s_waitcnt vmcnt(8)" ::: "memory");
    else if (p == 14) asm volatile("s_waitcnt vmcnt(4)" ::: "memory");
    else              asm volatile("s_waitcnt vmcnt(0)" ::: "memory");
    __builtin_amdgcn_s_barrier();   // raw barrier: loads stay in flight
    const char* pA = (const char*)lds4 + (p & 3) * 16384;
    const char* pB = pA + 8192;
    __builtin_amdgcn_s_setprio(1);
#pragma unroll
    for (int kk = 0; kk < 2; ++kk) {
      half8 af[2], bf[2];
#pragma unroll
      for (int mf = 0; mf < 2; ++mf)
        af[mf] = *(const half8*)(pA + ((((wm * 2 + mf) * 2 + kk) << 10) + lane * 16));
#pragma unroll
      for (int nf = 0; nf < 2; ++nf)
        bf[nf] = *(const half8*)(pB + ((((wn * 2 + nf) * 2 + kk) << 10) + lane * 16));
#pragma unroll
      for (int mf = 0; mf < 2; ++mf)
#pragma unroll
        for (int nf = 0; nf < 2; ++nf)
          acc[mf][nf] = __builtin_amdgcn_mfma_f32_16x16x32_f16(
              af[mf], bf[nf], acc[mf][nf], 0, 0, 0);
    }
    __builtin_amdgcn_s_setprio(0);
  }

#pragma unroll
  for (int mf = 0; mf < 2; ++mf)
#pragma unroll
    for (int nf = 0; nf < 2; ++nf) {
      int u = u0 + wn * 32 + nf * 16 + l15;
      int brow = b0 + wm * 32 + mf * 16 + (lk << 2);
#pragma unroll
      for (int j = 0; j < 4; ++j) {
        int b = brow + j;
        float p = (float)pr[((mf * 2 + nf) << 2) + j];
        float v = tanh_fast(acc[mf][nf][j] + p);
        outt[(size_t)b * (TS * NU) + u] = v;
        *(_Float16*)((char*)hnext + (((size_t)(bt * 16 + ut)) << 13) +
                     tile_off(b & 63, (u & 63) >> 3) + (u & 7) * 2) = (_Float16)v;
      }
    }
}

// ================= round-1 fallback path (small ws) =========================
__global__ __launch_bounds__(256) void wprep_lin(
    const float* __restrict__ Qw, const float* __restrict__ Bt,
    _Float16* __restrict__ W, int t0, int nt)
{
  __shared__ float ldsQ[32 * 257];
  __shared__ float ldsB[TS * 8];
  const int tid = threadIdx.x;
  const int k0 = blockIdx.x * 32;
  const int u0 = blockIdx.y * 32;
  for (int i = tid; i < TS * 8; i += 256) ldsB[i] = Bt[i];
  const float* qbase = Qw + (size_t)k0 * 8192 + (size_t)u0 * 8;
#pragma unroll
  for (int i = 0; i < 8; ++i) {
    int s = i * 256 + tid;
    int r = s >> 6, c4 = s & 63;
    float4 v = *(const float4*)(qbase + (size_t)r * 8192 + c4 * 4);
    float* d = &ldsQ[r * 257 + c4 * 4];
    d[0] = v.x; d[1] = v.y; d[2] = v.z; d[3] = v.w;
  }
  __syncthreads();
  const int kl = tid & 31;
  const int ug = tid >> 5;
#pragma unroll
  for (int p = 0; p < 4; ++p) {
    int uu = p * 8 + ug;
    float q[8];
#pragma unroll
    for (int j = 0; j < 8; ++j) q[j] = ldsQ[kl * 257 + uu * 8 + j];
    size_t obase = (size_t)(u0 + uu) * 2048 + k0 + kl;
    for (int tt = 0; tt < nt; ++tt) {
      const float* bt = &ldsB[(t0 + tt) * 8];
      float v = 0.f;
#pragma unroll
      for (int j = 0; j < 8; ++j) v += q[j] * bt[j];
      W[(size_t)tt * UD + obase] = (_Float16)v;
    }
  }
}

__global__ __launch_bounds__(256) void step_gemm(
    const float* __restrict__ xt, const float* __restrict__ hp, long hstride,
    const _Float16* __restrict__ Wt, const float* __restrict__ bias,
    float* __restrict__ outt)
{
  __shared__ _Float16 ldsA[2][64 * 64];
  __shared__ _Float16 ldsB[2][128 * 64];
  const int tid = threadIdx.x;
  const int b0 = blockIdx.x * 64;
  const int u0 = blockIdx.y * 128;
  const int lane = tid & 63;
  const int wv = tid >> 6;
  const int wm = wv >> 1, wn = wv & 1;
  const int l15 = lane & 15, lk = lane >> 4;

  float4 areg[4];
  uint4 breg[4];

  auto stage_load = [&](int kt) {
    const int k0 = kt * 64;
    const float* src; size_t stride; int koff;
    if (k0 < NU) { src = hp; stride = (size_t)hstride; koff = k0; }
    else { src = xt; stride = (size_t)TS * NI; koff = k0 - NU; }
#pragma unroll
    for (int i = 0; i < 4; ++i) {
      int s = i * 256 + tid;
      int r = s >> 4, c4 = s & 15;
      areg[i] = *(const float4*)(src + (size_t)(b0 + r) * stride + koff + c4 * 4);
    }
    const _Float16* wsrc = Wt + (size_t)u0 * 2048 + k0;
#pragma unroll
    for (int i = 0; i < 4; ++i) {
      int s = i * 256 + tid;
      int u = s >> 3, c8 = s & 7;
      breg[i] = *(const uint4*)(wsrc + (size_t)u * 2048 + c8 * 8);
    }
  };

  auto stage_write = [&](int buf) {
    char* pA = (char*)&ldsA[buf][0];
    char* pB = (char*)&ldsB[buf][0];
#pragma unroll
    for (int i = 0; i < 4; ++i) {
      int s = i * 256 + tid;
      int r = s >> 4, c4 = s & 15;
      half4v h;
      h[0] = (_Float16)areg[i].x; h[1] = (_Float16)areg[i].y;
      h[2] = (_Float16)areg[i].z; h[3] = (_Float16)areg[i].w;
      int off = (r * 128 + c4 * 8) ^ ((r & 7) << 4);
      *(half4v*)(pA + off) = h;
    }
#pragma unroll
    for (int i = 0; i < 4; ++i) {
      int s = i * 256 + tid;
      int u = s >> 3, c8 = s & 7;
      int off = (u * 128 + c8 * 16) ^ ((u & 7) << 4);
      *(uint4*)(pB + off) = breg[i];
    }
  };

  floatx4 acc[2][4] = {};

  auto compute = [&](int buf) {
    const char* pA = (const char*)&ldsA[buf][0];
    const char* pB = (const char*)&ldsB[buf][0];
#pragma unroll
    for (int kk = 0; kk < 2; ++kk) {
      half8 af[2], bf[4];
#pragma unroll
      for (int mf = 0; mf < 2; ++mf) {
        int r = wm * 32 + mf * 16 + l15;
        int off = r * 128 + ((((kk << 2) | lk) ^ (r & 7)) << 4);
        af[mf] = *(const half8*)(pA + off);
      }
#pragma unroll
      for (int nf = 0; nf < 4; ++nf) {
        int u = wn * 64 + nf * 16 + l15;
        int off = u * 128 + ((((kk << 2) | lk) ^ (u & 7)) << 4);
        bf[nf] = *(const half8*)(pB + off);
      }
#pragma unroll
      for (int mf = 0; mf < 2; ++mf)
#pragma unroll
        for (int nf = 0; nf < 4; ++nf)
          acc[mf][nf] =
              __builtin_amdgcn_mfma_f32_16x16x32_f16(af[mf], bf[nf], acc[mf][nf], 0, 0, 0);
    }
  };

  stage_load(0);
  stage_write(0);
  __syncthreads();
#pragma unroll 1
  for (int kt = 0; kt < 32; ++kt) {
    int cur = kt & 1;
    if (kt + 1 < 32) stage_load(kt + 1);
    compute(cur);
    if (kt + 1 < 32) stage_write(cur ^ 1);
    __syncthreads();
  }

#pragma unroll
  for (int mf = 0; mf < 2; ++mf)
#pragma unroll
    for (int nf = 0; nf < 4; ++nf) {
      int u = u0 + wn * 64 + nf * 16 + l15;
      float bv = bias[u];
      int brow = b0 + wm * 32 + mf * 16 + (lk << 2);
#pragma unroll
      for (int j = 0; j < 4; ++j) {
        float prev = acc[mf][nf][j] + bv;
        outt[(size_t)(brow + j) * (TS * NU) + u] = tanh_fast(prev);
      }
    }
}

extern "C" void kernel_launch(void* const* d_in, const int* in_sizes, int n_in,
                              void* d_out, int out_size, void* d_ws, size_t ws_size,
                              hipStream_t stream) {
  const float* x    = (const float*)d_in[0];
  const float* h0   = (const float*)d_in[1];
  const float* Qw   = (const float*)d_in[2];
  const float* bias = (const float*)d_in[3];
  const float* Bt   = (const float*)d_in[4];
  float* out = (float*)d_out;

  char* ws = (char*)d_ws;
  const size_t w_bytes    = (size_t)UD * TS * sizeof(_Float16);      // 167.8 MB
  const size_t pre_bytes  = (size_t)TS * NB * NU * sizeof(_Float16); // 167.8 MB
  const size_t slot_bytes = (size_t)NB * NU * sizeof(_Float16);      // 4 MB
  const size_t need = w_bytes + pre_bytes + 2 * slot_bytes;          // ~344 MB

  if (ws_size >= need) {
    _Float16* W   = (_Float16*)ws;
    _Float16* pre = (_Float16*)(ws + w_bytes);
    _Float16* hb  = (_Float16*)(ws + w_bytes + pre_bytes);
    const size_t SLOT = (size_t)NB * NU;  // elems

    wprep<<<dim3(32, 16), 256, 0, stream>>>(Qw, Bt, W);
    hinit<<<dim3(1024), 256, 0, stream>>>(h0, hb);  // slot 0
    xproj2<<<dim3(16, 8, TS), 256, 0, stream>>>(x, W, bias, pre);

    for (int t = 0; t < TS; ++t) {
      const _Float16* hprev = hb + (size_t)(t & 1) * SLOT;
      _Float16* hnext = hb + (size_t)((t + 1) & 1) * SLOT;
      serial2<<<dim3(512), 256, 0, stream>>>(
          W + (size_t)t * UD, pre + (size_t)t * NB * NU, hprev, hnext,
          out + (size_t)t * NU);
    }
  } else {
    // round-1 fallback (linear W layout)
    _Float16* W = (_Float16*)ws;
    const bool big = ws_size >= w_bytes;
    if (big) wprep_lin<<<dim3(64, 32), 256, 0, stream>>>(Qw, Bt, W, 0, TS);
    for (int t = 0; t < TS; ++t) {
      const _Float16* Wtp;
      if (big) {
        Wtp = W + (size_t)t * UD;
      } else {
        wprep_lin<<<dim3(64, 32), 256, 0, stream>>>(Qw, Bt, W, t, 1);
        Wtp = W;
      }
      const float* hp = (t == 0) ? h0 : out + (size_t)(t - 1) * NU;
      long hstride = (t == 0) ? NU : (long)TS * NU;
      step_gemm<<<dim3(32, 8), 256, 0, stream>>>(
          x + (size_t)t * NI, hp, hstride, Wtp, bias, out + (size_t)t * NU);
    }
  }
}

// Round 8
// 940.494 us; speedup vs baseline: 1.5686x; 1.0097x over previous
//
#include <hip/hip_runtime.h>
#include <hip/hip_fp16.h>

#define TS 40
#define NB 2048
#define NU 1024
#define NI 1024
#define ND 2048
#define UD (1024 * 2048)  // elems in one W_t (4 MB as f16)

typedef _Float16 half8 __attribute__((ext_vector_type(8)));
typedef _Float16 half4v __attribute__((ext_vector_type(4)));
typedef float floatx4 __attribute__((ext_vector_type(4)));

__device__ __forceinline__ float tanh_fast(float v) {
  float e = __expf(2.0f * v);
  return 1.0f - 2.0f / (e + 1.0f);  // inf-safe
}

// async global->LDS, 16B per lane
__device__ __forceinline__ void gload16(const void* g, void* l) {
  __builtin_amdgcn_global_load_lds(
      (const __attribute__((address_space(1))) void*)g,
      (__attribute__((address_space(3))) void*)l, 16, 0, 0);
}

// ===== fragment-major tile layout (verified R6/R7) ==========================
// tile = 64x64 f16 = 8192 B as 512 x 16B chunks.
// chunk(r,c8) = ((r>>4)*2 + (c8>>2))*64 + (c8&3)*16 + (r&15)
// MFMA frag read = wave-uniform base + lane*16 (conflict-free ds_read_b128).
__device__ __forceinline__ int tile_off(int r, int c8) {
  return (((((r >> 4) * 2 + (c8 >> 2)) << 6) + ((c8 & 3) << 4) + (r & 15)) << 4);
}
// xproj2-local A layout: XOR-swizzled so reg-staged *writes* are also
// conflict-free: byte = blk*1024 + q*256 + ((rl^q)<<4)
__device__ __forceinline__ int tile_off_x(int r, int c8) {
  int blk = (r >> 4) * 2 + (c8 >> 2), q = c8 & 3, rl = r & 15;
  return (blk << 10) + (q << 8) + (((rl ^ q)) << 4);
}

// W_tiled:  [t][ut 0..15][kt 0..31][8192B]  (kt<16: h-part, kt>=16: x-part)
// h_tiled:  [slot][bt 0..31][kt 0..15][8192B]
// pre:      [t][b][u] linear f16

// ---------------- wprep: Qw (fp32) -> W tiled f16 (R7, verified) ------------
__global__ __launch_bounds__(256) void wprep(
    const float* __restrict__ Qw, const float* __restrict__ Bt,
    _Float16* __restrict__ W)
{
  __shared__ _Float16 ldsQ[64 * 512];
  __shared__ float ldsB[TS * 8];
  const int tid = threadIdx.x;
  const int kt = blockIdx.x;   // 0..31
  const int ut = blockIdx.y;   // 0..15
  for (int i = tid; i < TS * 8; i += 256) ldsB[i] = Bt[i];
  const float* qb = Qw + (size_t)(kt * 64) * 8192 + ut * 512;
#pragma unroll
  for (int i = 0; i < 32; ++i) {
    int s = i * 256 + tid;
    int dk = s >> 7, c4 = s & 127;
    float4 v = *(const float4*)(qb + (size_t)dk * 8192 + c4 * 4);
    _Float16* d = &ldsQ[dk * 512 + c4 * 4];
    d[0] = (_Float16)v.x; d[1] = (_Float16)v.y;
    d[2] = (_Float16)v.z; d[3] = (_Float16)v.w;
  }
  __syncthreads();
  const int w = tid >> 6, lane = tid & 63;
  const int dur = lane & 7, ko = lane >> 3;
#pragma unroll 1
  for (int sp = 0; sp < 2; ++sp) {
    const int stripe = w * 2 + sp;
    const int du = stripe * 8 + dur;
    float Q[8][8];
#pragma unroll
    for (int j = 0; j < 8; ++j)
#pragma unroll
      for (int q = 0; q < 8; ++q)
        Q[j][q] = (float)ldsQ[(ko * 8 + j) * 512 + du * 8 + q];
    const int obase = tile_off(du, ko);
#pragma unroll 1
    for (int t = 0; t < TS; ++t) {
      float b[8];
#pragma unroll
      for (int q = 0; q < 8; ++q) b[q] = ldsB[t * 8 + q];
      half8 v;
#pragma unroll
      for (int j = 0; j < 8; ++j) {
        float s = 0.f;
#pragma unroll
        for (int q = 0; q < 8; ++q) s += Q[j][q] * b[q];
        v[j] = (_Float16)s;
      }
      size_t tile = ((size_t)t * 16 + ut) * 32 + kt;
      *(half8*)((char*)W + tile * 8192 + obase) = v;
    }
  }
}

// ---------------- hinit: h0 fp32 -> h tiled f16 (slot 0) (R7, verified) -----
__global__ __launch_bounds__(256) void hinit(const float* __restrict__ h0,
                                             _Float16* __restrict__ hb) {
  int g = blockIdx.x * 256 + threadIdx.x;
  int tile_id = g >> 9, rc = g & 511;
  int bt = tile_id >> 4, kt = tile_id & 15;
  int r = rc >> 3, c8 = rc & 7;
  const float* src = h0 + (size_t)(bt * 64 + r) * NU + kt * 64 + c8 * 8;
  float4 v0 = *(const float4*)src;
  float4 v1 = *(const float4*)(src + 4);
  half8 h;
  h[0] = (_Float16)v0.x; h[1] = (_Float16)v0.y;
  h[2] = (_Float16)v0.z; h[3] = (_Float16)v0.w;
  h[4] = (_Float16)v1.x; h[5] = (_Float16)v1.y;
  h[6] = (_Float16)v1.z; h[7] = (_Float16)v1.w;
  *(half8*)((char*)hb + (size_t)tile_id * 8192 + tile_off(r, c8)) = h;
}

// ---------------- xproj2: pre[t][b][u] = x_t @ Wx_t + bias ------------------
// 128x128 tile, grid (16,8,40), 4 waves of 64x64. A reg-staged with XOR-
// swizzled writes; B DMA'd, kept in flight across raw barriers (vmcnt(12)).
__global__ __launch_bounds__(256) void xproj2(
    const float* __restrict__ x, const _Float16* __restrict__ W,
    const float* __restrict__ bias, _Float16* __restrict__ pre)
{
  __shared__ char lds[2][32768];  // per buf: A 2 tiles 16KB | B 2 tiles 16KB
  const int tid = threadIdx.x;
  const int bt2 = blockIdx.x;   // 128 b-rows
  const int ut2 = blockIdx.y;   // 128 u-cols
  const int t   = blockIdx.z;
  const int lane = tid & 63, w = tid >> 6;
  const int wm2 = w >> 1, wn2 = w & 1;
  const int l15 = lane & 15, lk = lane >> 4;

  const float* xb = x + (size_t)(bt2 * 128) * (TS * NI) + (size_t)t * NI;
  const char* WB = (const char*)W + (((size_t)t * 16 + ut2 * 2) * 32 + 16) * 8192;

  float bv[4];
#pragma unroll
  for (int nf = 0; nf < 4; ++nf)
    bv[nf] = bias[ut2 * 128 + wn2 * 64 + nf * 16 + l15];

  float4 areg[8];

  auto loadA = [&](int p) {
#pragma unroll
    for (int i = 0; i < 8; ++i) {
      int s = i * 256 + tid;
      int r = s >> 4, c4 = s & 15;
      areg[i] = *(const float4*)(xb + (size_t)r * (TS * NI) + p * 64 + c4 * 4);
    }
  };
  auto issueB = [&](int p, int buf) {
    const char* gb = WB + (size_t)(w >> 1) * (32 * 8192) + (size_t)p * 8192 +
                     (w & 1) * 4096 + lane * 16;
    char* lb = lds[buf] + 16384 + (w >> 1) * 8192 + (w & 1) * 4096 + lane * 16;
    gload16(gb, lb);
    gload16(gb + 1024, lb + 1024);
    gload16(gb + 2048, lb + 2048);
    gload16(gb + 3072, lb + 3072);
  };
  auto writeA = [&](int buf) {
    char* pA = lds[buf];
#pragma unroll
    for (int i = 0; i < 8; ++i) {
      int s = i * 256 + tid;
      int r = s >> 4, c4 = s & 15;
      half4v h;
      h[0] = (_Float16)areg[i].x; h[1] = (_Float16)areg[i].y;
      h[2] = (_Float16)areg[i].z; h[3] = (_Float16)areg[i].w;
      *(half4v*)(pA + (r >> 6) * 8192 + tile_off_x(r & 63, c4 >> 1) +
                 (c4 & 1) * 8) = h;
    }
  };

  floatx4 acc[4][4] = {};
  const int lkq = lk << 8;
  const int swz = (l15 ^ lk) << 4;

  auto comp = [&](int buf) {
    const char* pA = lds[buf] + wm2 * 8192;
    const char* pB = lds[buf] + 16384 + wn2 * 8192;
    __builtin_amdgcn_s_setprio(1);
#pragma unroll
    for (int kk = 0; kk < 2; ++kk) {
      half8 af[4], bf[4];
#pragma unroll
      for (int mf = 0; mf < 4; ++mf)
        af[mf] = *(const half8*)(pA + (((mf * 2 + kk)) << 10) + lkq + swz);
#pragma unroll
      for (int nf = 0; nf < 4; ++nf)
        bf[nf] = *(const half8*)(pB + (((nf * 2 + kk)) << 10) + lane * 16);
#pragma unroll
      for (int mf = 0; mf < 4; ++mf)
#pragma unroll
        for (int nf = 0; nf < 4; ++nf)
          acc[mf][nf] = __builtin_amdgcn_mfma_f32_16x16x32_f16(
              af[mf], bf[nf], acc[mf][nf], 0, 0, 0);
    }
    __builtin_amdgcn_s_setprio(0);
  };

  // prologue: fill buf 0 (writeA's auto-wait covers only A; B(0) stays out)
  loadA(0);
  issueB(0, 0);
  writeA(0);
  asm volatile("s_waitcnt lgkmcnt(0)\n\ts_barrier" ::: "memory");
#pragma unroll 1
  for (int p = 0; p < 16; ++p) {
    int cur = p & 1;
    if (p + 1 < 16) { loadA(p + 1); issueB(p + 1, cur ^ 1); }
    if (p < 15)
      asm volatile("s_waitcnt vmcnt(12)\n\ts_barrier" ::: "memory");  // B(p) in LDS
    else
      asm volatile("s_waitcnt vmcnt(0)\n\ts_barrier" ::: "memory");
    comp(cur);
    if (p + 1 < 16) writeA(cur ^ 1);   // auto-waits newer-A only
    asm volatile("s_waitcnt lgkmcnt(0)\n\ts_barrier" ::: "memory");
  }

#pragma unroll
  for (int mf = 0; mf < 4; ++mf)
#pragma unroll
    for (int nf = 0; nf < 4; ++nf) {
      int u = ut2 * 128 + wn2 * 64 + nf * 16 + l15;
      int brow = bt2 * 128 + wm2 * 64 + mf * 16 + (lk << 2);
#pragma unroll
      for (int j = 0; j < 4; ++j)
        pre[((size_t)t * NB + brow + j) * NU + u] =
            (_Float16)(acc[mf][nf][j] + bv[nf]);
    }
}

// ---------------- serial2: h_t = tanh(h_{t-1} @ Wh_t + pre_t) ---------------
// 64x64 tile, 16 phases BK=64. Ring-4 DMA, depth-3 (issue p+3 POST-barrier),
// counted vmcnt (never 0 mid-loop). 512 blocks (2/CU).
__global__ __launch_bounds__(256) void serial2(
    const _Float16* __restrict__ Wh,    // W + t*UD (tiled)
    const _Float16* __restrict__ pret,  // pre + t*NB*NU (linear f16)
    const _Float16* __restrict__ hprev, // tiled
    _Float16* __restrict__ hnext,       // tiled
    float* __restrict__ outt)           // out + t*NU, row stride TS*NU
{
  __shared__ uint4 lds4[4096];          // 64 KB: 4 bufs x (A 8KB | B 8KB)
  const int tid = threadIdx.x, bid = blockIdx.x;
  const int bt = bid & 31, ut = bid >> 5;
  const int lane = tid & 63, w = tid >> 6;
  const int wm = w >> 1, wn = w & 1;
  const int l15 = lane & 15, lk = lane >> 4;
  const int b0 = bt * 64, u0 = ut * 64;

  // prefetch epilogue operand (oldest vmcnt entries, drained by first wait)
  _Float16 pr[16];
#pragma unroll
  for (int mf = 0; mf < 2; ++mf)
#pragma unroll
    for (int nf = 0; nf < 2; ++nf)
#pragma unroll
      for (int j = 0; j < 4; ++j)
        pr[((mf * 2 + nf) << 2) + j] = pret[
            (size_t)(b0 + wm * 32 + mf * 16 + (lk << 2) + j) * NU +
            (u0 + wn * 32 + nf * 16 + l15)];

  const char* Hb = (const char*)hprev + (size_t)bt * 16 * 8192;
  const char* Wb = (const char*)Wh + (size_t)ut * 32 * 8192;

  auto issue = [&](int kt) {
    char* la = (char*)lds4 + (kt & 3) * 16384 + w * 2048;
    const char* ga = Hb + (size_t)kt * 8192 + w * 2048 + lane * 16;
    const char* gb = Wb + (size_t)kt * 8192 + w * 2048 + lane * 16;
    gload16(ga, la);
    gload16(ga + 1024, la + 1024);
    gload16(gb, la + 8192);
    gload16(gb + 1024, la + 8192 + 1024);
  };

  floatx4 acc[2][2] = {};

  issue(0);
  issue(1);
  issue(2);
#pragma unroll 1
  for (int p = 0; p < 16; ++p) {
    // outstanding: phases p, p+1, p+2 (pr already drained after p=0)
    if (p < 14)       asm volatile("s_waitcnt vmcnt(8)" ::: "memory");
    else if (p == 14) asm volatile("s_waitcnt vmcnt(4)" ::: "memory");
    else              asm volatile("s_waitcnt vmcnt(0)" ::: "memory");
    __builtin_amdgcn_s_barrier();      // all waves' phase-p data in LDS
    if (p + 3 < 16) issue(p + 3);      // buf (p-1)&3 free: all did comp(p-1)
    const char* pA = (const char*)lds4 + (p & 3) * 16384;
    const char* pB = pA + 8192;
    __builtin_amdgcn_s_setprio(1);
#pragma unroll
    for (int kk = 0; kk < 2; ++kk) {
      half8 af[2], bf[2];
#pragma unroll
      for (int mf = 0; mf < 2; ++mf)
        af[mf] = *(const half8*)(pA + ((((wm * 2 + mf) * 2 + kk) << 10) + lane * 16));
#pragma unroll
      for (int nf = 0; nf < 2; ++nf)
        bf[nf] = *(const half8*)(pB + ((((wn * 2 + nf) * 2 + kk) << 10) + lane * 16));
#pragma unroll
      for (int mf = 0; mf < 2; ++mf)
#pragma unroll
        for (int nf = 0; nf < 2; ++nf)
          acc[mf][nf] = __builtin_amdgcn_mfma_f32_16x16x32_f16(
              af[mf], bf[nf], acc[mf][nf], 0, 0, 0);
    }
    __builtin_amdgcn_s_setprio(0);
  }

#pragma unroll
  for (int mf = 0; mf < 2; ++mf)
#pragma unroll
    for (int nf = 0; nf < 2; ++nf) {
      int u = u0 + wn * 32 + nf * 16 + l15;
      int brow = b0 + wm * 32 + mf * 16 + (lk << 2);
#pragma unroll
      for (int j = 0; j < 4; ++j) {
        int b = brow + j;
        float p = (float)pr[((mf * 2 + nf) << 2) + j];
        float v = tanh_fast(acc[mf][nf][j] + p);
        outt[(size_t)b * (TS * NU) + u] = v;
        *(_Float16*)((char*)hnext + (((size_t)(bt * 16 + ut)) << 13) +
                     tile_off(b & 63, (u & 63) >> 3) + (u & 7) * 2) = (_Float16)v;
      }
    }
}

// ================= round-1 fallback path (small ws) =========================
__global__ __launch_bounds__(256) void wprep_lin(
    const float* __restrict__ Qw, const float* __restrict__ Bt,
    _Float16* __restrict__ W, int t0, int nt)
{
  __shared__ float ldsQ[32 * 257];
  __shared__ float ldsB[TS * 8];
  const int tid = threadIdx.x;
  const int k0 = blockIdx.x * 32;
  const int u0 = blockIdx.y * 32;
  for (int i = tid; i < TS * 8; i += 256) ldsB[i] = Bt[i];
  const float* qbase = Qw + (size_t)k0 * 8192 + (size_t)u0 * 8;
#pragma unroll
  for (int i = 0; i < 8; ++i) {
    int s = i * 256 + tid;
    int r = s >> 6, c4 = s & 63;
    float4 v = *(const float4*)(qbase + (size_t)r * 8192 + c4 * 4);
    float* d = &ldsQ[r * 257 + c4 * 4];
    d[0] = v.x; d[1] = v.y; d[2] = v.z; d[3] = v.w;
  }
  __syncthreads();
  const int kl = tid & 31;
  const int ug = tid >> 5;
#pragma unroll
  for (int p = 0; p < 4; ++p) {
    int uu = p * 8 + ug;
    float q[8];
#pragma unroll
    for (int j = 0; j < 8; ++j) q[j] = ldsQ[kl * 257 + uu * 8 + j];
    size_t obase = (size_t)(u0 + uu) * 2048 + k0 + kl;
    for (int tt = 0; tt < nt; ++tt) {
      const float* bt = &ldsB[(t0 + tt) * 8];
      float v = 0.f;
#pragma unroll
      for (int j = 0; j < 8; ++j) v += q[j] * bt[j];
      W[(size_t)tt * UD + obase] = (_Float16)v;
    }
  }
}

__global__ __launch_bounds__(256) void step_gemm(
    const float* __restrict__ xt, const float* __restrict__ hp, long hstride,
    const _Float16* __restrict__ Wt, const float* __restrict__ bias,
    float* __restrict__ outt)
{
  __shared__ _Float16 ldsA[2][64 * 64];
  __shared__ _Float16 ldsB[2][128 * 64];
  const int tid = threadIdx.x;
  const int b0 = blockIdx.x * 64;
  const int u0 = blockIdx.y * 128;
  const int lane = tid & 63;
  const int wv = tid >> 6;
  const int wm = wv >> 1, wn = wv & 1;
  const int l15 = lane & 15, lk = lane >> 4;

  float4 areg[4];
  uint4 breg[4];

  auto stage_load = [&](int kt) {
    const int k0 = kt * 64;
    const float* src; size_t stride; int koff;
    if (k0 < NU) { src = hp; stride = (size_t)hstride; koff = k0; }
    else { src = xt; stride = (size_t)TS * NI; koff = k0 - NU; }
#pragma unroll
    for (int i = 0; i < 4; ++i) {
      int s = i * 256 + tid;
      int r = s >> 4, c4 = s & 15;
      areg[i] = *(const float4*)(src + (size_t)(b0 + r) * stride + koff + c4 * 4);
    }
    const _Float16* wsrc = Wt + (size_t)u0 * 2048 + k0;
#pragma unroll
    for (int i = 0; i < 4; ++i) {
      int s = i * 256 + tid;
      int u = s >> 3, c8 = s & 7;
      breg[i] = *(const uint4*)(wsrc + (size_t)u * 2048 + c8 * 8);
    }
  };

  auto stage_write = [&](int buf) {
    char* pA = (char*)&ldsA[buf][0];
    char* pB = (char*)&ldsB[buf][0];
#pragma unroll
    for (int i = 0; i < 4; ++i) {
      int s = i * 256 + tid;
      int r = s >> 4, c4 = s & 15;
      half4v h;
      h[0] = (_Float16)areg[i].x; h[1] = (_Float16)areg[i].y;
      h[2] = (_Float16)areg[i].z; h[3] = (_Float16)areg[i].w;
      int off = (r * 128 + c4 * 8) ^ ((r & 7) << 4);
      *(half4v*)(pA + off) = h;
    }
#pragma unroll
    for (int i = 0; i < 4; ++i) {
      int s = i * 256 + tid;
      int u = s >> 3, c8 = s & 7;
      int off = (u * 128 + c8 * 16) ^ ((u & 7) << 4);
      *(uint4*)(pB + off) = breg[i];
    }
  };

  floatx4 acc[2][4] = {};

  auto compute = [&](int buf) {
    const char* pA = (const char*)&ldsA[buf][0];
    const char* pB = (const char*)&ldsB[buf][0];
#pragma unroll
    for (int kk = 0; kk < 2; ++kk) {
      half8 af[2], bf[4];
#pragma unroll
      for (int mf = 0; mf < 2; ++mf) {
        int r = wm * 32 + mf * 16 + l15;
        int off = r * 128 + ((((kk << 2) | lk) ^ (r & 7)) << 4);
        af[mf] = *(const half8*)(pA + off);
      }
#pragma unroll
      for (int nf = 0; nf < 4; ++nf) {
        int u = wn * 64 + nf * 16 + l15;
        int off = u * 128 + ((((kk << 2) | lk) ^ (u & 7)) << 4);
        bf[nf] = *(const half8*)(pB + off);
      }
#pragma unroll
      for (int mf = 0; mf < 2; ++mf)
#pragma unroll
        for (int nf = 0; nf < 4; ++nf)
          acc[mf][nf] =
              __builtin_amdgcn_mfma_f32_16x16x32_f16(af[mf], bf[nf], acc[mf][nf], 0, 0, 0);
    }
  };

  stage_load(0);
  stage_write(0);
  __syncthreads();
#pragma unroll 1
  for (int kt = 0; kt < 32; ++kt) {
    int cur = kt & 1;
    if (kt + 1 < 32) stage_load(kt + 1);
    compute(cur);
    if (kt + 1 < 32) stage_write(cur ^ 1);
    __syncthreads();
  }

#pragma unroll
  for (int mf = 0; mf < 2; ++mf)
#pragma unroll
    for (int nf = 0; nf < 4; ++nf) {
      int u = u0 + wn * 64 + nf * 16 + l15;
      float bv = bias[u];
      int brow = b0 + wm * 32 + mf * 16 + (lk << 2);
#pragma unroll
      for (int j = 0; j < 4; ++j) {
        float prev = acc[mf][nf][j] + bv;
        outt[(size_t)(brow + j) * (TS * NU) + u] = tanh_fast(prev);
      }
    }
}

extern "C" void kernel_launch(void* const* d_in, const int* in_sizes, int n_in,
                              void* d_out, int out_size, void* d_ws, size_t ws_size,
                              hipStream_t stream) {
  const float* x    = (const float*)d_in[0];
  const float* h0   = (const float*)d_in[1];
  const float* Qw   = (const float*)d_in[2];
  const float* bias = (const float*)d_in[3];
  const float* Bt   = (const float*)d_in[4];
  float* out = (float*)d_out;

  char* ws = (char*)d_ws;
  const size_t w_bytes    = (size_t)UD * TS * sizeof(_Float16);      // 167.8 MB
  const size_t pre_bytes  = (size_t)TS * NB * NU * sizeof(_Float16); // 167.8 MB
  const size_t slot_bytes = (size_t)NB * NU * sizeof(_Float16);      // 4 MB
  const size_t need = w_bytes + pre_bytes + 2 * slot_bytes;          // ~344 MB

  if (ws_size >= need) {
    _Float16* W   = (_Float16*)ws;
    _Float16* pre = (_Float16*)(ws + w_bytes);
    _Float16* hb  = (_Float16*)(ws + w_bytes + pre_bytes);
    const size_t SLOT = (size_t)NB * NU;  // elems

    wprep<<<dim3(32, 16), 256, 0, stream>>>(Qw, Bt, W);
    hinit<<<dim3(1024), 256, 0, stream>>>(h0, hb);  // slot 0
    xproj2<<<dim3(16, 8, TS), 256, 0, stream>>>(x, W, bias, pre);

    for (int t = 0; t < TS; ++t) {
      const _Float16* hprev = hb + (size_t)(t & 1) * SLOT;
      _Float16* hnext = hb + (size_t)((t + 1) & 1) * SLOT;
      serial2<<<dim3(512), 256, 0, stream>>>(
          W + (size_t)t * UD, pre + (size_t)t * NB * NU, hprev, hnext,
          out + (size_t)t * NU);
    }
  } else {
    // round-1 fallback (linear W layout)
    _Float16* W = (_Float16*)ws;
    const bool big = ws_size >= w_bytes;
    if (big) wprep_lin<<<dim3(64, 32), 256, 0, stream>>>(Qw, Bt, W, 0, TS);
    for (int t = 0; t < TS; ++t) {
      const _Float16* Wtp;
      if (big) {
        Wtp = W + (size_t)t * UD;
      } else {
        wprep_lin<<<dim3(64, 32), 256, 0, stream>>>(Qw, Bt, W, t, 1);
        Wtp = W;
      }
      const float* hp = (t == 0) ? h0 : out + (size_t)(t - 1) * NU;
      long hstride = (t == 0) ? NU : (long)TS * NU;
      step_gemm<<<dim3(32, 8), 256, 0, stream>>>(
          x + (size_t)t * NI, hp, hstride, Wtp, bias, out + (size_t)t * NU);
    }
  }
}